// Round 14
// baseline (214.905 us; speedup 1.0000x reference)
//
#include <hip/hip_runtime.h>

// PointVoxelizer: bucketed sorted-unique over bounded key domain.
// combined = batch*GXYZ + x*YZ + y*GZ + z in [0, 3.2e8).
// Points partitioned by key>>18 into 1221 buckets (2^18 cells = 32KB LDS
// bitmap); all random access in LDS.
// R13 restructure: 8 -> 5 dispatches (gaps ~3us each + idle bubbles):
//  - k2b folded into k3: each k3 block wave-scans tot[NB] in LDS (block 0
//    publishes boff for k4).
//  - k5 folded into k4 via last-block election (threadfence + atomic ctr;
//    dispatch-order-independent): last k4 block scans dcnt -> drank_tbl, nvox.
//  - k6+k7 merged into one role-split dispatch (emit | map+tailpad).
//
// Dispatches:
//   k1_keys_hist : keys -> upt; per-(chunk,bucket) LDS hist; zeroes ctr
//   k2a_chunk_pre: per-bucket exclusive prefix over chunks -> tot
//   k3_scatter   : LDS scan tot -> boff (blk0 publishes); scatter keys; pos[i]
//   k4_rank      : per-bucket LDS bitmap + swizzled word-prefix -> dcnt, dk,
//                  mapval; LAST block scans dcnt -> drank_tbl + n_voxels
//   k6_emit_map  : [0,NB): decode dk -> coords/feats rows;
//                  rest: out_map[i] + tail-pad rows >= n_voxels

namespace {

constexpr int GX = 1000, GY = 1000, GZ = 80;
constexpr int YZ = GY * GZ;                 // 80,000
constexpr int GXYZ = GX * YZ;               // 80,000,000
constexpr int TOTAL_CELLS = GXYZ * 4;       // 320,000,000 (< 2^31)
constexpr int BBITS = 18;
constexpr int BCELLS = 1 << BBITS;          // 262,144 cells / bucket
constexpr int NB = (TOTAL_CELLS + BCELLS - 1) >> BBITS;  // 1221
constexpr int BWORDS = BCELLS / 32;         // 8192 u32 (32KB LDS bitmap)
constexpr int NCHUNK = 512;
static_assert(NCHUNK % 64 == 0, "k2a wave scan");
static_assert(NB <= 1280, "k3 LDS scan: 256 thr x 5");
static_assert(NB <= 2048, "k4 tail scan: 1024 thr x 2");

// ws layout (bytes):
//   [0,    8e6)   upt    u32[N]
//   [8e6, 16e6)   pk     u32[N]
//   [16e6,24e6)   pos    u32[N]
//   [24e6,32e6)   mapval u32[N]
//   [32e6,40e6)   dk     u32[N]
//   [40e6,42.6e6) hist   u32[NCHUNK][NB]
//   [43e6,..)     tot, boff, dcnt, drank, ctr
constexpr size_t OFF_PK    = 8000000;
constexpr size_t OFF_POS   = 16000000;
constexpr size_t OFF_MVAL  = 24000000;
constexpr size_t OFF_DK    = 32000000;
constexpr size_t OFF_HIST  = 40000000;
constexpr size_t OFF_TOT   = 43000000;
constexpr size_t OFF_BOFF  = 43100000;
constexpr size_t OFF_DCNT  = 43200000;
constexpr size_t OFF_DRANK = 43300000;
constexpr size_t OFF_CTR   = 43400000;

__device__ __forceinline__ int sw(int w) {  // rank-word -> LDS slot swizzle
  return ((w & 7) << 10) | (w >> 3);
}

__global__ void k1_keys_hist(const float* __restrict__ pts, const int* __restrict__ bi,
                             unsigned* __restrict__ upt, unsigned* __restrict__ hist,
                             unsigned* __restrict__ ctr, int n, int cpb) {
  __shared__ unsigned h[NB];
  const int c = blockIdx.x;
  if (c == 0 && threadIdx.x == 0) *ctr = 0;  // for k4's last-block election
  for (int b = threadIdx.x; b < NB; b += blockDim.x) h[b] = 0;
  __syncthreads();
  const int lo = c * cpb, hi = min(n, lo + cpb);
  for (int i = lo + threadIdx.x; i < hi; i += blockDim.x) {
    // Bit-exact mirror of reference: fp32 add/div/floor (non-contractible).
    float px = pts[3 * i + 0], py = pts[3 * i + 1], pz = pts[3 * i + 2];
    int vx = (int)floorf((px + 50.0f) / 0.1f);
    int vy = (int)floorf((py + 50.0f) / 0.1f);
    int vz = (int)floorf((pz + 5.0f) / 0.1f);
    bool valid = (vx >= 0) & (vy >= 0) & (vz >= 0) & (vx < GX) & (vy < GY) & (vz < GZ);
    unsigned u = 0xFFFFFFFFu;
    if (valid) {
      u = (unsigned)(bi[i] * GXYZ + vx * YZ + vy * GZ + vz);
      atomicAdd(&h[u >> BBITS], 1u);
    }
    upt[i] = u;
  }
  __syncthreads();
  for (int b = threadIdx.x; b < NB; b += blockDim.x)
    hist[(size_t)c * NB + b] = h[b];  // contiguous flush, no global atomics
}

// One wave per bucket: exclusive prefix of hist[*][b] across chunks (in place),
// bucket total -> tot[b].
__global__ void k2a_chunk_pre(unsigned* __restrict__ hist, unsigned* __restrict__ tot) {
  const int wid = (blockIdx.x * blockDim.x + threadIdx.x) >> 6;
  const int lane = threadIdx.x & 63;
  if (wid >= NB) return;
  unsigned run = 0;
  for (int c0 = 0; c0 < NCHUNK; c0 += 64) {
    const size_t idx = (size_t)(c0 + lane) * NB + wid;
    unsigned v = hist[idx];
    unsigned inc = v;
    for (int o = 1; o < 64; o <<= 1) {
      unsigned t = __shfl_up(inc, o);
      if (lane >= o) inc += t;
    }
    hist[idx] = run + inc - v;
    run += __shfl(inc, 63);
  }
  if (lane == 63) tot[wid] = run;
}

// Scatter keys into bucket regions. Each block first wave-scans tot[NB] in LDS
// to get boff (k2b folded in); block 0 publishes boff[NB+1] for k4.
__global__ void k3_scatter(const unsigned* __restrict__ upt, const unsigned* __restrict__ hist,
                           const unsigned* __restrict__ tot, unsigned* __restrict__ boff,
                           unsigned* __restrict__ pk, unsigned* __restrict__ pos,
                           int n, int cpb) {
  __shared__ unsigned arr[NB];   // exclusive prefix of tot, then cursors
  __shared__ unsigned s4w[4];
  const int tid = threadIdx.x;
  const int lane = tid & 63, wv = tid >> 6;
  const int c = blockIdx.x;

  // LDS scan: arr[b] = sum(tot[0..b))
  unsigned lv[5];
  unsigned t = 0;
  #pragma unroll
  for (int j = 0; j < 5; j++) {
    int k = tid * 5 + j;
    unsigned v = (k < NB) ? tot[k] : 0u;
    lv[j] = t;
    t += v;
  }
  unsigned incl = t;
  #pragma unroll
  for (int o = 1; o < 64; o <<= 1) {
    unsigned u = __shfl_up(incl, o);
    if (lane >= o) incl += u;
  }
  if (lane == 63) s4w[wv] = incl;
  __syncthreads();
  unsigned woff = 0;
  for (int j = 0; j < wv; j++) woff += s4w[j];
  unsigned excl = woff + incl - t;
  #pragma unroll
  for (int j = 0; j < 5; j++) {
    int k = tid * 5 + j;
    if (k < NB) arr[k] = excl + lv[j];
  }
  __syncthreads();
  if (c == 0) {  // publish boff for k4 (reads arr; must precede in-place add)
    for (int k = tid; k < NB; k += 256) boff[k] = arr[k];
    if (tid == 0) boff[NB] = s4w[0] + s4w[1] + s4w[2] + s4w[3];
  }
  __syncthreads();
  // cursors: cur[b] = boff[b] + hist[c][b]  (in place)
  for (int b = tid; b < NB; b += 256) arr[b] += hist[(size_t)c * NB + b];
  __syncthreads();

  const int lo = c * cpb, hi = min(n, lo + cpb);
  for (int i = lo + tid; i < hi; i += 256) {
    unsigned u = upt[i];
    if (u == 0xFFFFFFFFu) continue;
    unsigned p = atomicAdd(&arr[u >> BBITS], 1u);
    pk[p] = u;
    pos[i] = p;
  }
}

// Per-bucket: LDS bitmap + swizzled word-prefix -> dcnt, dk, mapval.
// Last-arriving block (threadfence + atomic ctr election) scans dcnt ->
// drank_tbl[NB] + n_voxels (k5 folded in).
__global__ void __launch_bounds__(1024) k4_rank(
    const unsigned* __restrict__ pk, const unsigned* __restrict__ boff,
    unsigned* __restrict__ dcnt, unsigned* __restrict__ dk,
    unsigned* __restrict__ mapval, unsigned* __restrict__ ctr,
    unsigned* __restrict__ drank_tbl, float* __restrict__ out_nvox) {
  __shared__ unsigned bits[BWORDS];  // 32KB, rank-swizzled via sw()
  __shared__ unsigned wpre[BWORDS];  // 32KB, rank-swizzled
  __shared__ unsigned s16[16];
  __shared__ unsigned lastF;
  const int tid = threadIdx.x;
  const int bid = blockIdx.x;
  const int lane = tid & 63, wid = tid >> 6;

  for (int w = tid; w < BWORDS; w += 1024) bits[w] = 0;
  __syncthreads();
  const unsigned lo = boff[bid], hi = boff[bid + 1];
  const unsigned base = (unsigned)bid << BBITS;
  for (unsigned p = lo + tid; p < hi; p += 1024) {
    unsigned local = pk[p] - base;
    atomicOr(&bits[sw(local >> 5)], 1u << (local & 31));
  }
  __syncthreads();

  // popcount prefix: thread owns rank-words 8t..8t+7 at slots {t,1024+t,..}
  unsigned c8[8];
  unsigned t = 0;
  #pragma unroll
  for (int j = 0; j < 8; j++) {
    unsigned p = __popc(bits[j * 1024 + tid]);
    c8[j] = t;
    t += p;
  }
  unsigned incl = t;
  #pragma unroll
  for (int o = 1; o < 64; o <<= 1) {
    unsigned u = __shfl_up(incl, o);
    if (lane >= o) incl += u;
  }
  if (lane == 63) s16[wid] = incl;
  __syncthreads();
  unsigned woff = 0;
  for (int j = 0; j < wid; j++) woff += s16[j];
  const unsigned excl = woff + incl - t;
  #pragma unroll
  for (int j = 0; j < 8; j++) wpre[j * 1024 + tid] = excl + c8[j];
  if (tid == 1023) dcnt[bid] = excl + t;

  // enumerate set bits in rank order -> compacted distinct keys (register
  // prefixes only; no barrier needed before this)
  const unsigned dkb = lo;
  #pragma unroll
  for (int j = 0; j < 8; j++) {
    unsigned m = bits[j * 1024 + tid];
    unsigned r = excl + c8[j];
    const unsigned lbase = (unsigned)(tid * 8 + j) << 5;
    while (m) {
      int bit = __ffs(m) - 1;
      m &= m - 1;
      dk[dkb + r] = base + lbase + (unsigned)bit;
      r++;
    }
  }
  __syncthreads();  // wpre fully written before random reads below

  // per-pair LOCAL rank -> mapval[p] (contiguous write)
  for (unsigned p = lo + tid; p < hi; p += 1024) {
    unsigned local = pk[p] - base;
    int slot = sw((int)(local >> 5));
    mapval[p] = wpre[slot] + (unsigned)__popc(bits[slot] & ((1u << (local & 31)) - 1u));
  }

  // ---- last-block election: scan dcnt -> drank_tbl + n_voxels ----
  __syncthreads();
  if (tid == 0) {
    __threadfence();  // make dcnt (and all prior stores) device-visible
    lastF = (atomicAdd(ctr, 1u) == (unsigned)(NB - 1)) ? 1u : 0u;
  }
  __syncthreads();
  if (lastF) {
    unsigned v0 = (2 * tid < NB)
        ? __hip_atomic_load(&dcnt[2 * tid], __ATOMIC_RELAXED, __HIP_MEMORY_SCOPE_AGENT) : 0u;
    unsigned v1 = (2 * tid + 1 < NB)
        ? __hip_atomic_load(&dcnt[2 * tid + 1], __ATOMIC_RELAXED, __HIP_MEMORY_SCOPE_AGENT) : 0u;
    unsigned t2 = v0 + v1;
    unsigned inc2 = t2;
    #pragma unroll
    for (int o = 1; o < 64; o <<= 1) {
      unsigned u = __shfl_up(inc2, o);
      if (lane >= o) inc2 += u;
    }
    if (lane == 63) s16[wid] = inc2;
    __syncthreads();
    unsigned w2 = 0;
    for (int j = 0; j < wid; j++) w2 += s16[j];
    unsigned e2 = w2 + inc2 - t2;
    if (2 * tid < NB) drank_tbl[2 * tid] = e2;
    if (2 * tid + 1 < NB) drank_tbl[2 * tid + 1] = e2 + v0;
    if (tid == 1023) *out_nvox = (float)(e2 + t2);
  }
}

// Role-split: [0,NB) decode dk -> coords/feats rows; rest: per-row map +
// tail-pad (rows >= n_voxels). Write sets disjoint.
__global__ void k6_emit_map(const unsigned* __restrict__ dk, const unsigned* __restrict__ boff,
                            const unsigned* __restrict__ dcnt,
                            const unsigned* __restrict__ drank_tbl,
                            const unsigned* __restrict__ upt, const unsigned* __restrict__ pos,
                            const unsigned* __restrict__ mapval,
                            const float* __restrict__ nvox_f,
                            float* __restrict__ out_coords, float* __restrict__ out_feats,
                            float* __restrict__ out_map, int n) {
  const int tid = threadIdx.x;
  const int bid = blockIdx.x;

  if (bid < NB) {
    const unsigned drank = drank_tbl[bid];
    const unsigned dc = dcnt[bid];
    const unsigned dkb = boff[bid];
    for (unsigned j = tid; j < dc; j += 256) {
      unsigned u = dk[dkb + j];
      int bat = (int)(u / (unsigned)GXYZ);
      int rem = (int)(u % (unsigned)GXYZ);
      int x = rem / YZ, ry = rem % YZ;
      int y = ry / GZ, z = ry % GZ;
      const size_t r = drank + j;
      float* cc = out_coords + r * 4;
      cc[0] = (float)bat; cc[1] = (float)z; cc[2] = (float)y; cc[3] = (float)x;
      float* ff = out_feats + r * 3;
      ff[0] = -50.0f + ((float)x + 0.5f) * 0.1f;
      ff[1] = -50.0f + ((float)y + 0.5f) * 0.1f;
      ff[2] = -5.0f + ((float)z + 0.5f) * 0.1f;
    }
    return;
  }

  const int i = (bid - NB) * 256 + tid;
  if (i >= n) return;
  unsigned u = upt[i];
  if (u == 0xFFFFFFFFu) {
    out_map[i] = -1.0f;
  } else {
    out_map[i] = (float)(drank_tbl[u >> BBITS] + mapval[pos[i]]);
  }
  const unsigned nv = (unsigned)*nvox_f;
  if ((unsigned)i >= nv) {
    float* c = out_coords + (size_t)i * 4;
    c[0] = -1.0f; c[1] = -1.0f; c[2] = -1.0f; c[3] = -1.0f;
    float* f = out_feats + (size_t)i * 3;
    f[0] = 0.0f; f[1] = 0.0f; f[2] = 0.0f;
  }
}

}  // namespace

extern "C" void kernel_launch(void* const* d_in, const int* in_sizes, int n_in,
                              void* d_out, int out_size, void* d_ws, size_t ws_size,
                              hipStream_t stream) {
  const int N = in_sizes[0] / 3;
  const float* pts = (const float*)d_in[0];
  const int* bi = (const int*)d_in[1];
  float* out = (float*)d_out;

  unsigned* upt   = (unsigned*)d_ws;
  unsigned* pk    = (unsigned*)((char*)d_ws + OFF_PK);
  unsigned* pos   = (unsigned*)((char*)d_ws + OFF_POS);
  unsigned* mval  = (unsigned*)((char*)d_ws + OFF_MVAL);
  unsigned* dk    = (unsigned*)((char*)d_ws + OFF_DK);
  unsigned* hist  = (unsigned*)((char*)d_ws + OFF_HIST);
  unsigned* tot   = (unsigned*)((char*)d_ws + OFF_TOT);
  unsigned* boff  = (unsigned*)((char*)d_ws + OFF_BOFF);
  unsigned* dcnt  = (unsigned*)((char*)d_ws + OFF_DCNT);
  unsigned* drank = (unsigned*)((char*)d_ws + OFF_DRANK);
  unsigned* ctr   = (unsigned*)((char*)d_ws + OFF_CTR);

  float* out_coords = out;            // [N,4]
  float* out_feats  = out + 4LL * N;  // [N,3]
  float* out_map    = out + 7LL * N;  // [N]
  float* out_nvox   = out + 8LL * N;  // scalar

  const int cpb = (N + NCHUNK - 1) / NCHUNK;
  const int row_blocks = (N + 255) / 256;

  k1_keys_hist<<<NCHUNK, 256, 0, stream>>>(pts, bi, upt, hist, ctr, N, cpb);
  k2a_chunk_pre<<<(NB * 64 + 255) / 256, 256, 0, stream>>>(hist, tot);
  k3_scatter<<<NCHUNK, 256, 0, stream>>>(upt, hist, tot, boff, pk, pos, N, cpb);
  k4_rank<<<NB, 1024, 0, stream>>>(pk, boff, dcnt, dk, mval, ctr, drank, out_nvox);
  k6_emit_map<<<NB + row_blocks, 256, 0, stream>>>(dk, boff, dcnt, drank, upt, pos,
                                                   mval, out_nvox, out_coords,
                                                   out_feats, out_map, N);
}